// Round 11
// baseline (661.309 us; speedup 1.0000x reference)
//
#include <hip/hip_runtime.h>
#include <hip/hip_bf16.h>

#define B_ 32
#define L_ 512
#define D_ 768
#define M_ (B_*L_)
#define NEGV (-9e15f)

typedef __hip_bfloat16 bf16;
typedef short v8s __attribute__((ext_vector_type(8)));
typedef float v4f __attribute__((ext_vector_type(4)));

static __device__ __forceinline__ unsigned short f2b(float f) {
    __hip_bfloat16 h = __float2bfloat16(f);
    return *reinterpret_cast<unsigned short*>(&h);
}

static __device__ __forceinline__ float fast_tanh(float x) {
    x = fminf(fmaxf(x, -15.f), 15.f);
    float e2 = __expf(2.f * x);
    return (e2 - 1.f) / (e2 + 1.f);
}

// pack 8 fp32 -> v8s of bf16
static __device__ __forceinline__ v8s pack8(const float* p) {
    v8s r;
    #pragma unroll
    for (int i = 0; i < 8; i++) r[i] = (short)f2b(p[i]);
    return r;
}

// ---- setup: seg info (blocks 0..31) + bias-fold vecs (32..800) ----
__global__ __launch_bounds__(256) void k_setup(const int* ids, const int* pad_p, const int* sep_p, int* seg,
                        const float* Wk_sup, const float* bq_sup,
                        const float* Wk_con, const float* bq_con,
                        const float* Wk_rep, const float* bq_rep,
                        const float* Wq_con, const float* bk_con,
                        float* __restrict__ vecs) {
    int bid = blockIdx.x, t = threadIdx.x;
    if (bid < 32) {                       // --- seg ---
        int b = bid;
        __shared__ int red[256];
        int pad = *pad_p, sepid = *sep_p;
        int minsep = L_, vcount = 0;
        for (int l = t; l < L_; l += 256) {
            int id = ids[b*L_ + l];
            if (id == sepid && l < minsep) minsep = l;
            if (id != pad) vcount++;
        }
        red[t] = minsep; __syncthreads();
        for (int s = 128; s > 0; s >>= 1) { if (t < s) red[t] = min(red[t], red[t+s]); __syncthreads(); }
        int sepmin = red[0]; __syncthreads();
        red[t] = vcount; __syncthreads();
        for (int s = 128; s > 0; s >>= 1) { if (t < s) red[t] += red[t+s]; __syncthreads(); }
        if (t == 0) {
            int vlen = red[0];
            int fb = vlen / 2; if (fb < 1) fb = 1; if (fb > L_-2) fb = L_-2;
            int sep = (sepmin < L_) ? sepmin : fb;
            seg[b*2] = sep; seg[b*2+1] = vlen;
        }
        return;
    }
    {                                     // --- vecs: 3073 wave-dots ---
        int gw = (bid - 32)*4 + (t >> 6);
        int lane = t & 63;
        if (gw > 3072) return;
        if (gw == 3072) {
            float s = 0.f;
            #pragma unroll
            for (int i = 0; i < D_/64; i++) s += bq_con[lane + 64*i] * bk_con[lane + 64*i];
            #pragma unroll
            for (int m = 32; m; m >>= 1) s += __shfl_xor(s, m);
            if (lane == 0) vecs[3072] = s;
            return;
        }
        int sel = gw / D_, row = gw % D_;
        const float* Wrow; const float* bv;
        switch (sel) {
            case 0: Wrow = Wk_sup + (size_t)row*D_; bv = bq_sup; break;
            case 1: Wrow = Wk_con + (size_t)row*D_; bv = bq_con; break;
            case 2: Wrow = Wk_rep + (size_t)row*D_; bv = bq_rep; break;
            default: Wrow = Wq_con + (size_t)row*D_; bv = bk_con; break;
        }
        float s = 0.f;
        #pragma unroll
        for (int i = 0; i < D_/64; i++) s += Wrow[lane + 64*i] * bv[lane + 64*i];
        #pragma unroll
        for (int m = 32; m; m >>= 1) s += __shfl_xor(s, m);
        if (lane == 0) vecs[gw] = s;
    }
}

// ---- fused: cast x row to bf16 + 5 per-row dots (one x read total) ----
__global__ void k_prep(const float* __restrict__ x, const float* __restrict__ Wa,
                       const float* __restrict__ ba, const float* __restrict__ vecs,
                       bf16* __restrict__ xb,
                       float* __restrict__ anom, float* __restrict__ csup,
                       float* __restrict__ ccon, float* __restrict__ crep,
                       float* __restrict__ rcon) {
    int gw = (blockIdx.x*blockDim.x + threadIdx.x) >> 6;
    int lane = threadIdx.x & 63;
    if (gw >= M_) return;
    const float* xr = x + (size_t)gw*D_;
    bf16* xbr = xb + (size_t)gw*D_;
    float sa=0.f, s0=0.f, s1=0.f, s2=0.f, s3=0.f;
    #pragma unroll
    for (int i = 0; i < D_/64; i++) {
        int o = i*64 + lane;
        float xv = xr[o];
        xbr[o] = __float2bfloat16(xv);
        sa += xv * Wa[o];
        s0 += xv * vecs[o];
        s1 += xv * vecs[768 + o];
        s2 += xv * vecs[1536 + o];
        s3 += xv * vecs[2304 + o];
    }
    #pragma unroll
    for (int m = 32; m; m >>= 1) {
        sa += __shfl_xor(sa, m); s0 += __shfl_xor(s0, m); s1 += __shfl_xor(s1, m);
        s2 += __shfl_xor(s2, m); s3 += __shfl_xor(s3, m);
    }
    if (lane == 0) {
        anom[gw] = sa + ba[0];
        csup[gw] = s0; ccon[gw] = s1; crep[gw] = s2; rcon[gw] = s3;
    }
}

// ------- gate: masked softmax over false segment + zero-init of accum buffers -------
__global__ void k_gate(const float* __restrict__ anom, const int* __restrict__ ids,
                       const int* seg, const int* pad_p, float* __restrict__ gate,
                       float4* __restrict__ zbuf, int zcount4) {
    int b = blockIdx.x, t = threadIdx.x;
    for (int i = b*256 + t; i < zcount4; i += 32*256)
        zbuf[i] = (float4){0.f,0.f,0.f,0.f};
    int sep = seg[b*2]; int pad = *pad_p;
    __shared__ float red[256];
    float a0[2]; bool f0[2];
    float mx = -__builtin_inff();
    #pragma unroll
    for (int j = 0; j < 2; j++) {
        int l = t + j*256;
        bool fm = (l < sep) && (ids[b*L_+l] != pad);
        float a = anom[b*L_+l];
        f0[j] = fm; a0[j] = a;
        if (fm) mx = fmaxf(mx, a);
    }
    red[t] = mx; __syncthreads();
    for (int s = 128; s; s >>= 1) { if (t < s) red[t] = fmaxf(red[t], red[t+s]); __syncthreads(); }
    mx = red[0]; __syncthreads();
    float e[2]; float se = 0.f;
    #pragma unroll
    for (int j = 0; j < 2; j++) { e[j] = f0[j] ? __expf(a0[j]-mx) : 0.f; se += e[j]; }
    red[t] = se; __syncthreads();
    for (int s = 128; s; s >>= 1) { if (t < s) red[t] += red[t+s]; __syncthreads(); }
    se = red[0];
    float inv = 1.f / fmaxf(se, 1e-8f);
    #pragma unroll
    for (int j = 0; j < 2; j++) { int l = t + j*256; gate[b*L_+l] = e[j]*inv; }
}

// ---- AT_h = Wk_h @ Wq_h^T from fp32 weights, 64x64 tiles, grid (12,12,3) ----
__global__ __launch_bounds__(256) void k_wqk(const float* Wq_sup, const float* Wk_sup,
                                             const float* Wq_con, const float* Wk_con,
                                             const float* Wq_rep, const float* Wk_rep,
                                             bf16* __restrict__ AT) {
    int h = blockIdx.z;
    const float* Asrc; const float* Bsrc;
    switch (h) { case 0: Asrc=Wk_sup; Bsrc=Wq_sup; break;
                 case 1: Asrc=Wk_con; Bsrc=Wq_con; break;
                 default: Asrc=Wk_rep; Bsrc=Wq_rep; }
    bf16* outp = AT + (size_t)h*D_*D_;
    __shared__ bf16 As[64*32];
    __shared__ bf16 Bs[64*32];
    int t = threadIdx.x;
    int wave = t >> 6, lane = t & 63;
    int quad = lane >> 4, l16 = lane & 15;
    int wm = wave >> 1, wn = wave & 1;
    int row0 = blockIdx.x * 64;
    int col0 = blockIdx.y * 64;

    v4f acc[2][2];
    #pragma unroll
    for (int i = 0; i < 2; i++)
        #pragma unroll
        for (int j = 0; j < 2; j++) acc[i][j] = (v4f){0.f,0.f,0.f,0.f};

    int srow = lane >> 2;
    int sk8  = lane & 3;
    int slot = (sk8 << 4) | srow;
    for (int k0 = 0; k0 < D_; k0 += 32) {
        #pragma unroll
        for (int cc = 0; cc < 2; cc++) {
            int c = wave + cc*4;
            const float* src = (c < 4)
                ? Asrc + (size_t)(row0 + c*16 + srow)*D_ + k0 + sk8*8
                : Bsrc + (size_t)(col0 + (c-4)*16 + srow)*D_ + k0 + sk8*8;
            float tmp[8];
            *reinterpret_cast<float4*>(tmp)     = *reinterpret_cast<const float4*>(src);
            *reinterpret_cast<float4*>(tmp + 4) = *reinterpret_cast<const float4*>(src + 4);
            v8s packed = pack8(tmp);
            if (c < 4) *reinterpret_cast<v8s*>(&As[(c    )*512 + slot*8]) = packed;
            else       *reinterpret_cast<v8s*>(&Bs[(c - 4)*512 + slot*8]) = packed;
        }
        __syncthreads();
        v8s af[2], bf[2];
        #pragma unroll
        for (int i = 0; i < 2; i++)
            af[i] = *reinterpret_cast<const v8s*>(&As[(wm*2 + i)*512 + lane*8]);
        #pragma unroll
        for (int j = 0; j < 2; j++)
            bf[j] = *reinterpret_cast<const v8s*>(&Bs[(wn*2 + j)*512 + lane*8]);
        #pragma unroll
        for (int i = 0; i < 2; i++)
            #pragma unroll
            for (int j = 0; j < 2; j++)
                acc[i][j] = __builtin_amdgcn_mfma_f32_16x16x32_bf16(af[i], bf[j], acc[i][j], 0, 0, 0);
        __syncthreads();
    }
    #pragma unroll
    for (int i = 0; i < 2; i++)
        #pragma unroll
        for (int j = 0; j < 2; j++) {
            int n = col0 + wn*32 + j*16 + l16;
            #pragma unroll
            for (int r = 0; r < 4; r++) {
                int m = row0 + wm*32 + i*16 + quad*4 + r;
                outp[(size_t)m*D_ + n] = __float2bfloat16(acc[i][j][r]);
            }
        }
}

// ====== FUSED gmat+score: per (b, 16-row tile), head-at-a-time =============
// Phase 1 (per head): G_h[16][768] = x_tile @ A_h  (A-frag from Xs LDS,
//   B-frag = AT_h rows from L2), C-layout -> identity-layout Gs via ds_write.
// Phase 2 (per head): score MFMAs over option col-tiles (kf from global),
//   accumulating S (sup) / C (con) / R (rep). Then softmax + gate-reduce.
__global__ __launch_bounds__(256) void k_gscore(const bf16* __restrict__ xb,
                                                const bf16* __restrict__ AT,
                                                const int* __restrict__ ids,
                                                const int* __restrict__ seg,
                                                const float* __restrict__ gate,
                                                const int* pad_p,
                                                const float* __restrict__ csup,
                                                const float* __restrict__ ccon,
                                                const float* __restrict__ crep,
                                                const float* __restrict__ rcon,
                                                const float* __restrict__ vecs,
                                                float* __restrict__ w_sup,
                                                float* __restrict__ w_rep) {
    int b = blockIdx.x, rt = blockIdx.y;
    int sep = seg[b*2];
    int r0 = rt*16;
    if (r0 >= sep) return;
    int pad = *pad_p;
    int wave = threadIdx.x >> 6, lane = threadIdx.x & 63;
    int quad = lane >> 4, l16 = lane & 15;
    int lane8 = lane*8;
    const float inv = 0.03608439182435161f;       // 1/sqrt(768)
    int ct0 = (sep + 1) >> 4;

    __shared__ bf16 Xs[12288];    // 24,576 B: x_tile identity layout [kb][lane*8]
    __shared__ bf16 Gs[12288];    // 24,576 B: current head's G tile, identity layout

    const bf16* xrow = xb + (size_t)b*L_*D_;

    // --- stage x_tile (coalesced read -> identity slot) ---
    {
        int srow = lane >> 2, sk8 = lane & 3;
        int slot = (sk8 << 4) | srow;
        for (int kb = wave; kb < 24; kb += 4) {
            v8s v = *reinterpret_cast<const v8s*>(xrow + (size_t)(r0 + srow)*D_ + kb*32 + sk8*8);
            *reinterpret_cast<v8s*>(&Xs[kb*512 + slot*8]) = v;
        }
    }

    // option col-tiles
    int tile[6]; bool act[6];
    #pragma unroll
    for (int i = 0; i < 6; i++) {
        int ctv = ct0 + wave + 4*i;
        act[i] = ctv < 32;
        tile[i] = act[i] ? ctv : 31;
    }
    int koff[6];
    #pragma unroll
    for (int i = 0; i < 6; i++) koff[i] = (tile[i]*16 + l16)*D_ + quad*8;

    // phase-1 AT row offsets: 12 v-tiles per wave (vt = wave + 4*gi)
    int voff[12];
    #pragma unroll
    for (int gi = 0; gi < 12; gi++)
        voff[gi] = ((wave + 4*gi)*16 + l16)*D_ + quad*8;

    v4f S[6], C[6], R[6];
    #pragma unroll
    for (int i = 0; i < 6; i++) { S[i] = (v4f){0,0,0,0}; C[i] = (v4f){0,0,0,0}; R[i] = (v4f){0,0,0,0}; }

    __syncthreads();   // Xs ready

    #pragma unroll
    for (int h = 0; h < 3; h++) {
        const bf16* ATh = AT + (size_t)h*D_*D_;
        // ---- phase 1: G_h tile into Gs ----
        v4f gacc[12];
        #pragma unroll
        for (int gi = 0; gi < 12; gi++) gacc[gi] = (v4f){0,0,0,0};
        for (int kb = 0; kb < 24; kb++) {
            v8s xa = *reinterpret_cast<const v8s*>(&Xs[kb*512 + lane8]);
            #pragma unroll
            for (int gi = 0; gi < 12; gi++) {
                v8s bt = *reinterpret_cast<const v8s*>(ATh + voff[gi] + kb*32);
                gacc[gi] = __builtin_amdgcn_mfma_f32_16x16x32_bf16(xa, bt, gacc[gi], 0, 0, 0);
            }
        }
        if (h > 0) __syncthreads();   // ensure prior head's Gs reads are done before overwrite
        #pragma unroll
        for (int gi = 0; gi < 12; gi++) {
            int v = (wave + 4*gi)*16 + l16;
            int kb = v >> 5, q8 = (v >> 3) & 3, j = v & 7;
            int base = kb*512 + q8*128 + j;
            #pragma unroll
            for (int r = 0; r < 4; r++)
                Gs[base + (quad*4 + r)*8] = __float2bfloat16(gacc[gi][r]);
        }
        __syncthreads();              // Gs ready
        // ---- phase 2: score MFMAs for this head ----
        if (h == 0) {
            for (int kb = 0, k0 = 0; kb < 24; kb++, k0 += 32) {
                v8s ga = *reinterpret_cast<const v8s*>(&Gs[kb*512 + lane8]);
                #pragma unroll
                for (int i = 0; i < 6; i++) {
                    v8s kf = *reinterpret_cast<const v8s*>(xrow + koff[i] + k0);
                    S[i] = __builtin_amdgcn_mfma_f32_16x16x32_bf16(ga, kf, S[i], 0, 0, 0);
                }
            }
        } else if (h == 1) {
            for (int kb = 0, k0 = 0; kb < 24; kb++, k0 += 32) {
                v8s ga = *reinterpret_cast<const v8s*>(&Gs[kb*512 + lane8]);
                #pragma unroll
                for (int i = 0; i < 6; i++) {
                    v8s kf = *reinterpret_cast<const v8s*>(xrow + koff[i] + k0);
                    C[i] = __builtin_amdgcn_mfma_f32_16x16x32_bf16(ga, kf, C[i], 0, 0, 0);
                }
            }
        } else {
            for (int kb = 0, k0 = 0; kb < 24; kb++, k0 += 32) {
                v8s ga = *reinterpret_cast<const v8s*>(&Gs[kb*512 + lane8]);
                #pragma unroll
                for (int i = 0; i < 6; i++) {
                    v8s kf = *reinterpret_cast<const v8s*>(xrow + koff[i] + k0);
                    R[i] = __builtin_amdgcn_mfma_f32_16x16x32_bf16(ga, kf, R[i], 0, 0, 0);
                }
            }
        }
    }

    // ---- epilogue: logits, softmax, gate-weighted column reduce ----
    bool opt[6];
    float cs_v[6], cc_v[6], cr_v[6];
    #pragma unroll
    for (int i = 0; i < 6; i++) {
        int c = tile[i]*16 + l16;
        opt[i] = act[i] && (c > sep) && (ids[b*L_ + c] != pad);
        cs_v[i] = csup[b*L_ + c];
        cc_v[i] = ccon[b*L_ + c];
        cr_v[i] = crep[b*L_ + c];
    }
    float rc_r[4];
    #pragma unroll
    for (int r = 0; r < 4; r++) rc_r[r] = rcon[b*L_ + r0 + quad*4 + r];
    float dcon = vecs[3072];

    #pragma unroll
    for (int i = 0; i < 6; i++)
        #pragma unroll
        for (int r = 0; r < 4; r++) {
            float sl = (S[i][r] + cs_v[i]) * inv;
            float cl = fast_tanh((C[i][r] + cc_v[i] + rc_r[r] + dcon) * inv);
            float rl = (R[i][r] + cr_v[i]) * inv + cl;
            S[i][r] = sl; R[i][r] = rl;
        }

    float mxs[4], mxr[4];
    #pragma unroll
    for (int r = 0; r < 4; r++) { mxs[r] = NEGV; mxr[r] = NEGV; }
    #pragma unroll
    for (int i = 0; i < 6; i++)
        #pragma unroll
        for (int r = 0; r < 4; r++) {
            float sv = opt[i] ? S[i][r] : NEGV;
            float rv = opt[i] ? R[i][r] : NEGV;
            mxs[r] = fmaxf(mxs[r], sv);
            mxr[r] = fmaxf(mxr[r], rv);
        }
    #pragma unroll
    for (int d = 1; d < 16; d <<= 1)
        #pragma unroll
        for (int r = 0; r < 4; r++) {
            mxs[r] = fmaxf(mxs[r], __shfl_xor(mxs[r], d));
            mxr[r] = fmaxf(mxr[r], __shfl_xor(mxr[r], d));
        }
    __shared__ float redm[2][16][4];
    __shared__ float reds[2][16][4];
    if (l16 == 0)
        #pragma unroll
        for (int r = 0; r < 4; r++) {
            redm[0][quad*4+r][wave] = mxs[r];
            redm[1][quad*4+r][wave] = mxr[r];
        }
    __syncthreads();
    #pragma unroll
    for (int r = 0; r < 4; r++) {
        int row = quad*4 + r;
        mxs[r] = fmaxf(fmaxf(redm[0][row][0], redm[0][row][1]), fmaxf(redm[0][row][2], redm[0][row][3]));
        mxr[r] = fmaxf(fmaxf(redm[1][row][0], redm[1][row][1]), fmaxf(redm[1][row][2], redm[1][row][3]));
    }

    float ssum[4] = {0,0,0,0}, rsum[4] = {0,0,0,0};
    #pragma unroll
    for (int i = 0; i < 6; i++)
        #pragma unroll
        for (int r = 0; r < 4; r++) {
            float es = opt[i] ? __expf(S[i][r] - mxs[r]) : 0.f;
            float er = opt[i] ? __expf(R[i][r] - mxr[r]) : 0.f;
            S[i][r] = es; R[i][r] = er;
            ssum[r] += es; rsum[r] += er;
        }
    #pragma unroll
    for (int d = 1; d < 16; d <<= 1)
        #pragma unroll
        for (int r = 0; r < 4; r++) {
            ssum[r] += __shfl_xor(ssum[r], d);
            rsum[r] += __shfl_xor(rsum[r], d);
        }
    if (l16 == 0)
        #pragma unroll
        for (int r = 0; r < 4; r++) {
            reds[0][quad*4+r][wave] = ssum[r];
            reds[1][quad*4+r][wave] = rsum[r];
        }
    __syncthreads();
    float gs_[4], gr_[4];
    #pragma unroll
    for (int r = 0; r < 4; r++) {
        int row = quad*4 + r;
        float st = reds[0][row][0] + reds[0][row][1] + reds[0][row][2] + reds[0][row][3];
        float rtot = reds[1][row][0] + reds[1][row][1] + reds[1][row][2] + reds[1][row][3];
        float g = gate[b*L_ + r0 + row];
        gs_[r] = g / st;
        gr_[r] = g / rtot;
    }

    #pragma unroll
    for (int i = 0; i < 6; i++) {
        float cs = 0.f, cr = 0.f;
        #pragma unroll
        for (int r = 0; r < 4; r++) { cs += S[i][r]*gs_[r]; cr += R[i][r]*gr_[r]; }
        cs += __shfl_xor(cs, 16); cs += __shfl_xor(cs, 32);
        cr += __shfl_xor(cr, 16); cr += __shfl_xor(cr, 32);
        if (act[i] && quad == 0) {
            int c = tile[i]*16 + l16;
            atomicAdd(&w_sup[b*L_ + c], cs);
            atomicAdd(&w_rep[b*L_ + c], cr);
        }
    }
}

// ---- 3 gemvs over L (bf16 x): partials into fused[32][2304] via atomics --
__global__ __launch_bounds__(256) void k_fused(const bf16* __restrict__ xb,
                                               const float* __restrict__ gate,
                                               const float* __restrict__ wrep,
                                               const float* __restrict__ wsup,
                                               float* __restrict__ fused) {
    int b = blockIdx.x, ch = blockIdx.y, t = threadIdx.x;
    int l0 = ch*64;
    const bf16* xb_ = xb + (size_t)b*L_*D_;
    float a0=0,a1=0,a2=0, r0=0,r1=0,r2=0, s0=0,s1=0,s2=0;
    for (int l = l0; l < l0+64; l++) {
        float g = gate[b*L_+l], wr = wrep[b*L_+l], wv = wsup[b*L_+l];
        if (g == 0.f && wr == 0.f && wv == 0.f) continue;
        float x0 = __bfloat162float(xb_[l*D_ + t]);
        float x1 = __bfloat162float(xb_[l*D_ + t + 256]);
        float x2 = __bfloat162float(xb_[l*D_ + t + 512]);
        a0 += g*x0;  a1 += g*x1;  a2 += g*x2;
        r0 += wr*x0; r1 += wr*x1; r2 += wr*x2;
        s0 += wv*x0; s1 += wv*x1; s2 += wv*x2;
    }
    float* f = fused + (size_t)b*2304;
    atomicAdd(&f[t],        a0); atomicAdd(&f[t+256],      a1); atomicAdd(&f[t+512],      a2);
    atomicAdd(&f[768+t],    r0); atomicAdd(&f[768+t+256],  r1); atomicAdd(&f[768+t+512],  r2);
    atomicAdd(&f[1536+t],   s0); atomicAdd(&f[1536+t+256], s1); atomicAdd(&f[1536+t+512], s2);
}

// ---- MLP layer 1, split-K: partial sums into h1pre via atomics ----
__global__ __launch_bounds__(256) void k_mlp1(const float* __restrict__ fused,
                                              const float* __restrict__ W1,
                                              float* __restrict__ h1pre) {
    int c0 = blockIdx.x*64, k0 = blockIdx.y*128;
    int t = threadIdx.x;
    __shared__ float fsl[32][132];
    for (int i = t*4; i < 32*128; i += 1024) {
        int b = i >> 7, k = i & 127;
        const float4 v = *reinterpret_cast<const float4*>(&fused[(size_t)b*2304 + k0 + k]);
        fsl[b][k] = v.x; fsl[b][k+1] = v.y; fsl[b][k+2] = v.z; fsl[b][k+3] = v.w;
    }
    __syncthreads();
    int c = c0 + (t & 63), bg = (t >> 6) * 8;
    float acc[8] = {0,0,0,0,0,0,0,0};
    for (int k = 0; k < 128; k++) {
        float w = W1[(size_t)(k0+k)*D_ + c];
        #pragma unroll
        for (int b = 0; b < 8; b++) acc[b] += fsl[bg+b][k] * w;
    }
    #pragma unroll
    for (int b = 0; b < 8; b++) atomicAdd(&h1pre[(size_t)(bg+b)*D_ + c], acc[b]);
}

// ---- MLP layer 2, split-K: relu(h1pre+b1) on load; partials into opre ----
__global__ __launch_bounds__(256) void k_mlp2(const float* __restrict__ h1pre,
                                              const float* __restrict__ b1,
                                              const float* __restrict__ W2,
                                              float* __restrict__ opre) {
    int c0 = blockIdx.x*64, k0 = blockIdx.y*128;
    int t = threadIdx.x;
    __shared__ float fsl[32][132];
    for (int i = t*4; i < 32*128; i += 1024) {
        int b = i >> 7, k = i & 127;
        const float4 v = *reinterpret_cast<const float4*>(&h1pre[(size_t)b*D_ + k0 + k]);
        const float4 bb = *reinterpret_cast<const float4*>(&b1[k0 + k]);
        fsl[b][k]   = fmaxf(v.x + bb.x, 0.f);
        fsl[b][k+1] = fmaxf(v.y + bb.y, 0.f);
        fsl[b][k+2] = fmaxf(v.z + bb.z, 0.f);
        fsl[b][k+3] = fmaxf(v.w + bb.w, 0.f);
    }
    __syncthreads();
    int c = c0 + (t & 63), bg = (t >> 6) * 8;
    float acc[8] = {0,0,0,0,0,0,0,0};
    for (int k = 0; k < 128; k++) {
        float w = W2[(size_t)(k0+k)*D_ + c];
        #pragma unroll
        for (int b = 0; b < 8; b++) acc[b] += fsl[bg+b][k] * w;
    }
    #pragma unroll
    for (int b = 0; b < 8; b++) atomicAdd(&opre[(size_t)(bg+b)*D_ + c], acc[b]);
}

// ---- bias2 + LayerNorm: one block per batch ----
__global__ __launch_bounds__(256) void k_ln(const float* __restrict__ opre,
                                            const float* __restrict__ b2,
                                            const float* __restrict__ lng,
                                            const float* __restrict__ lnb,
                                            float* __restrict__ out) {
    int b = blockIdx.x, t = threadIdx.x;
    __shared__ float red[256];
    float v0 = opre[(size_t)b*D_ + t]       + b2[t];
    float v1 = opre[(size_t)b*D_ + t + 256] + b2[t+256];
    float v2 = opre[(size_t)b*D_ + t + 512] + b2[t+512];
    float sum = v0+v1+v2, sq = v0*v0+v1*v1+v2*v2;
    red[t] = sum; __syncthreads();
    for (int s = 128; s; s >>= 1) { if (t < s) red[t] += red[t+s]; __syncthreads(); }
    sum = red[0]; __syncthreads();
    red[t] = sq; __syncthreads();
    for (int s = 128; s; s >>= 1) { if (t < s) red[t] += red[t+s]; __syncthreads(); }
    sq = red[0];
    float mu = sum / 768.f;
    float var = sq / 768.f - mu*mu;
    float rstd = rsqrtf(var + 1e-5f);
    out[(size_t)b*D_ + t]       = (v0-mu)*rstd*lng[t]     + lnb[t];
    out[(size_t)b*D_ + t + 256] = (v1-mu)*rstd*lng[t+256] + lnb[t+256];
    out[(size_t)b*D_ + t + 512] = (v2-mu)*rstd*lng[t+512] + lnb[t+512];
}

extern "C" void kernel_launch(void* const* d_in, const int* in_sizes, int n_in,
                              void* d_out, int out_size, void* d_ws, size_t ws_size,
                              hipStream_t stream) {
    const float* x      = (const float*)d_in[0];
    const int*   ids    = (const int*)d_in[1];
    const int*   pad_p  = (const int*)d_in[2];
    const int*   sep_p  = (const int*)d_in[3];
    const float* W_anom = (const float*)d_in[4];
    const float* b_anom = (const float*)d_in[5];
    const float* Wq_sup = (const float*)d_in[6];  const float* bq_sup = (const float*)d_in[7];
    const float* Wk_sup = (const float*)d_in[8];  const float* bk_sup = (const float*)d_in[9];
    const float* Wq_con = (const float*)d_in[10]; const float* bq_con = (const float*)d_in[11];
    const float* Wk_con = (const float*)d_in[12]; const float* bk_con = (const float*)d_in[13];
    const float* Wq_rep = (const float*)d_in[14]; const float* bq_rep = (const float*)d_in[15];
    const float* Wk_rep = (const float*)d_in[16]; const float* bk_rep = (const float*)d_in[17];
    const float* W1     = (const float*)d_in[18]; const float* b1     = (const float*)d_in[19];
    const float* W2     = (const float*)d_in[20]; const float* b2     = (const float*)d_in[21];
    const float* lng    = (const float*)d_in[22]; const float* lnb    = (const float*)d_in[23];
    float* out = (float*)d_out;

    char* w = (char*)d_ws;
    bf16*  xb    = (bf16*)(w);                      // 25,165,824
    bf16*  AT    = (bf16*)(w + 25165824);           //  3,538,944
    float* vecs  = (float*)(w + 28704768);          //     16,384
    float* anom  = (float*)(w + 28721152);          //     65,536
    float* gate  = (float*)(w + 28786688);          //     65,536
    float* csup  = (float*)(w + 28852224);          //     65,536
    float* ccon  = (float*)(w + 28917760);          //     65,536
    float* crep  = (float*)(w + 28983296);          //     65,536
    float* rcon  = (float*)(w + 29048832);          //     65,536
    float* wsup  = (float*)(w + 29114368);          //     65,536
    float* wrep  = (float*)(w + 29179904);          //     65,536
    float* fused = (float*)(w + 29245440);          //    294,912
    float* h1pre = (float*)(w + 29540352);          //     98,304
    float* opre  = (float*)(w + 29638656);          //     98,304
    int*   seg   = (int*)  (w + 29736960);          //        256

    k_setup<<<801, 256, 0, stream>>>(ids, pad_p, sep_p, seg,
                                     Wk_sup, bq_sup, Wk_con, bq_con, Wk_rep, bq_rep, Wq_con, bk_con, vecs);
    k_prep<<<4096, 256, 0, stream>>>(x, W_anom, b_anom, vecs, xb, anom, csup, ccon, crep, rcon);
    // k_gate also zero-inits wsup..opre (contiguous 622,592 B = 38,912 float4)
    k_gate<<<B_, 256, 0, stream>>>(anom, ids, seg, pad_p, gate, (float4*)wsup, 38912);
    k_wqk<<<dim3(12, 12, 3), 256, 0, stream>>>(Wq_sup, Wk_sup, Wq_con, Wk_con, Wq_rep, Wk_rep, AT);
    k_gscore<<<dim3(B_, 16), 256, 0, stream>>>(xb, AT, ids, seg, gate, pad_p,
                                               csup, ccon, crep, rcon, vecs, wsup, wrep);
    k_fused<<<dim3(B_, 8), 256, 0, stream>>>(xb, gate, wrep, wsup, fused);
    k_mlp1<<<dim3(12, 18), 256, 0, stream>>>(fused, W1, h1pre);
    k_mlp2<<<dim3(12, 6), 256, 0, stream>>>(h1pre, b1, W2, opre);
    k_ln<<<B_, 256, 0, stream>>>(opre, b2, lng, lnb, out);
}

// Round 12
// 336.700 us; speedup vs baseline: 1.9641x; 1.9641x over previous
//
#include <hip/hip_runtime.h>
#include <hip/hip_bf16.h>

#define B_ 32
#define L_ 512
#define D_ 768
#define M_ (B_*L_)
#define NEGV (-9e15f)

typedef __hip_bfloat16 bf16;
typedef short v8s __attribute__((ext_vector_type(8)));
typedef float v4f __attribute__((ext_vector_type(4)));

static __device__ __forceinline__ unsigned short f2b(float f) {
    __hip_bfloat16 h = __float2bfloat16(f);
    return *reinterpret_cast<unsigned short*>(&h);
}

static __device__ __forceinline__ float fast_tanh(float x) {
    x = fminf(fmaxf(x, -15.f), 15.f);
    float e2 = __expf(2.f * x);
    return (e2 - 1.f) / (e2 + 1.f);
}

// async global->LDS, 16B per lane; lds dest is wave-uniform base + lane*16 (global addr may scatter)
static __device__ __forceinline__ void gl_lds16(const void* g, void* l) {
    __builtin_amdgcn_global_load_lds(
        (const __attribute__((address_space(1))) unsigned int*)g,
        (__attribute__((address_space(3))) unsigned int*)l, 16, 0, 0);
}

// pack 8 fp32 -> v8s of bf16
static __device__ __forceinline__ v8s pack8(const float* p) {
    v8s r;
    #pragma unroll
    for (int i = 0; i < 8; i++) r[i] = (short)f2b(p[i]);
    return r;
}

// ---- setup: seg info (blocks 0..31) + bias-fold vecs (32..800) ----
__global__ __launch_bounds__(256) void k_setup(const int* ids, const int* pad_p, const int* sep_p, int* seg,
                        const float* Wk_sup, const float* bq_sup,
                        const float* Wk_con, const float* bq_con,
                        const float* Wk_rep, const float* bq_rep,
                        const float* Wq_con, const float* bk_con,
                        float* __restrict__ vecs) {
    int bid = blockIdx.x, t = threadIdx.x;
    if (bid < 32) {                       // --- seg ---
        int b = bid;
        __shared__ int red[256];
        int pad = *pad_p, sepid = *sep_p;
        int minsep = L_, vcount = 0;
        for (int l = t; l < L_; l += 256) {
            int id = ids[b*L_ + l];
            if (id == sepid && l < minsep) minsep = l;
            if (id != pad) vcount++;
        }
        red[t] = minsep; __syncthreads();
        for (int s = 128; s > 0; s >>= 1) { if (t < s) red[t] = min(red[t], red[t+s]); __syncthreads(); }
        int sepmin = red[0]; __syncthreads();
        red[t] = vcount; __syncthreads();
        for (int s = 128; s > 0; s >>= 1) { if (t < s) red[t] += red[t+s]; __syncthreads(); }
        if (t == 0) {
            int vlen = red[0];
            int fb = vlen / 2; if (fb < 1) fb = 1; if (fb > L_-2) fb = L_-2;
            int sep = (sepmin < L_) ? sepmin : fb;
            seg[b*2] = sep; seg[b*2+1] = vlen;
        }
        return;
    }
    {                                     // --- vecs: 3073 wave-dots ---
        int gw = (bid - 32)*4 + (t >> 6);
        int lane = t & 63;
        if (gw > 3072) return;
        if (gw == 3072) {
            float s = 0.f;
            #pragma unroll
            for (int i = 0; i < D_/64; i++) s += bq_con[lane + 64*i] * bk_con[lane + 64*i];
            #pragma unroll
            for (int m = 32; m; m >>= 1) s += __shfl_xor(s, m);
            if (lane == 0) vecs[3072] = s;
            return;
        }
        int sel = gw / D_, row = gw % D_;
        const float* Wrow; const float* bv;
        switch (sel) {
            case 0: Wrow = Wk_sup + (size_t)row*D_; bv = bq_sup; break;
            case 1: Wrow = Wk_con + (size_t)row*D_; bv = bq_con; break;
            case 2: Wrow = Wk_rep + (size_t)row*D_; bv = bq_rep; break;
            default: Wrow = Wq_con + (size_t)row*D_; bv = bk_con; break;
        }
        float s = 0.f;
        #pragma unroll
        for (int i = 0; i < D_/64; i++) s += Wrow[lane + 64*i] * bv[lane + 64*i];
        #pragma unroll
        for (int m = 32; m; m >>= 1) s += __shfl_xor(s, m);
        if (lane == 0) vecs[gw] = s;
    }
}

// ---- fused: (blocks 0..4095) cast x to bf16 + 5 per-row dots
// ---- (blocks 4096..4527) AT_h = Wk_h @ Wq_h^T, 64x64 tiles ----
__global__ __launch_bounds__(256) void k_prepw(const float* __restrict__ x, const float* __restrict__ Wa,
                       const float* __restrict__ ba, const float* __restrict__ vecs,
                       bf16* __restrict__ xb,
                       float* __restrict__ anom, float* __restrict__ csup,
                       float* __restrict__ ccon, float* __restrict__ crep,
                       float* __restrict__ rcon,
                       const float* Wq_sup, const float* Wk_sup,
                       const float* Wq_con, const float* Wk_con,
                       const float* Wq_rep, const float* Wk_rep,
                       bf16* __restrict__ AT) {
    __shared__ bf16 As[64*32];
    __shared__ bf16 Bs[64*32];
    int bid = blockIdx.x;
    if (bid < 4096) {                     // ---- prep part ----
        int gw = (bid*256 + threadIdx.x) >> 6;
        int lane = threadIdx.x & 63;
        const float* xr = x + (size_t)gw*D_;
        bf16* xbr = xb + (size_t)gw*D_;
        float sa=0.f, s0=0.f, s1=0.f, s2=0.f, s3=0.f;
        #pragma unroll
        for (int i = 0; i < D_/64; i++) {
            int o = i*64 + lane;
            float xv = xr[o];
            xbr[o] = __float2bfloat16(xv);
            sa += xv * Wa[o];
            s0 += xv * vecs[o];
            s1 += xv * vecs[768 + o];
            s2 += xv * vecs[1536 + o];
            s3 += xv * vecs[2304 + o];
        }
        #pragma unroll
        for (int m = 32; m; m >>= 1) {
            sa += __shfl_xor(sa, m); s0 += __shfl_xor(s0, m); s1 += __shfl_xor(s1, m);
            s2 += __shfl_xor(s2, m); s3 += __shfl_xor(s3, m);
        }
        if (lane == 0) {
            anom[gw] = sa + ba[0];
            csup[gw] = s0; ccon[gw] = s1; crep[gw] = s2; rcon[gw] = s3;
        }
        return;
    }
    // ---- wqk part ----
    int wid = bid - 4096;                 // 0..431
    int h = wid / 144, rem = wid % 144;
    int bx = rem / 12, by = rem % 12;
    const float* Asrc; const float* Bsrc;
    switch (h) { case 0: Asrc=Wk_sup; Bsrc=Wq_sup; break;
                 case 1: Asrc=Wk_con; Bsrc=Wq_con; break;
                 default: Asrc=Wk_rep; Bsrc=Wq_rep; }
    bf16* outp = AT + (size_t)h*D_*D_;
    int t = threadIdx.x;
    int wave = t >> 6, lane = t & 63;
    int quad = lane >> 4, l16 = lane & 15;
    int wm = wave >> 1, wn = wave & 1;
    int row0 = bx * 64;
    int col0 = by * 64;

    v4f acc[2][2];
    #pragma unroll
    for (int i = 0; i < 2; i++)
        #pragma unroll
        for (int j = 0; j < 2; j++) acc[i][j] = (v4f){0.f,0.f,0.f,0.f};

    int srow = lane >> 2;
    int sk8  = lane & 3;
    int slot = (sk8 << 4) | srow;
    for (int k0 = 0; k0 < D_; k0 += 32) {
        #pragma unroll
        for (int cc = 0; cc < 2; cc++) {
            int c = wave + cc*4;
            const float* src = (c < 4)
                ? Asrc + (size_t)(row0 + c*16 + srow)*D_ + k0 + sk8*8
                : Bsrc + (size_t)(col0 + (c-4)*16 + srow)*D_ + k0 + sk8*8;
            float tmp[8];
            *reinterpret_cast<float4*>(tmp)     = *reinterpret_cast<const float4*>(src);
            *reinterpret_cast<float4*>(tmp + 4) = *reinterpret_cast<const float4*>(src + 4);
            v8s packed = pack8(tmp);
            if (c < 4) *reinterpret_cast<v8s*>(&As[(c    )*512 + slot*8]) = packed;
            else       *reinterpret_cast<v8s*>(&Bs[(c - 4)*512 + slot*8]) = packed;
        }
        __syncthreads();
        v8s af[2], bf[2];
        #pragma unroll
        for (int i = 0; i < 2; i++)
            af[i] = *reinterpret_cast<const v8s*>(&As[(wm*2 + i)*512 + lane*8]);
        #pragma unroll
        for (int j = 0; j < 2; j++)
            bf[j] = *reinterpret_cast<const v8s*>(&Bs[(wn*2 + j)*512 + lane*8]);
        #pragma unroll
        for (int i = 0; i < 2; i++)
            #pragma unroll
            for (int j = 0; j < 2; j++)
                acc[i][j] = __builtin_amdgcn_mfma_f32_16x16x32_bf16(af[i], bf[j], acc[i][j], 0, 0, 0);
        __syncthreads();
    }
    #pragma unroll
    for (int i = 0; i < 2; i++)
        #pragma unroll
        for (int j = 0; j < 2; j++) {
            int n = col0 + wn*32 + j*16 + l16;
            #pragma unroll
            for (int r = 0; r < 4; r++) {
                int m = row0 + wm*32 + i*16 + quad*4 + r;
                outp[(size_t)m*D_ + n] = __float2bfloat16(acc[i][j][r]);
            }
        }
}

// ------- gate: masked softmax over false segment + zero-init of accum buffers -------
__global__ void k_gate(const float* __restrict__ anom, const int* __restrict__ ids,
                       const int* seg, const int* pad_p, float* __restrict__ gate,
                       float4* __restrict__ zbuf, int zcount4) {
    int b = blockIdx.x, t = threadIdx.x;
    for (int i = b*256 + t; i < zcount4; i += 32*256)
        zbuf[i] = (float4){0.f,0.f,0.f,0.f};
    int sep = seg[b*2]; int pad = *pad_p;
    __shared__ float red[256];
    float a0[2]; bool f0[2];
    float mx = -__builtin_inff();
    #pragma unroll
    for (int j = 0; j < 2; j++) {
        int l = t + j*256;
        bool fm = (l < sep) && (ids[b*L_+l] != pad);
        float a = anom[b*L_+l];
        f0[j] = fm; a0[j] = a;
        if (fm) mx = fmaxf(mx, a);
    }
    red[t] = mx; __syncthreads();
    for (int s = 128; s; s >>= 1) { if (t < s) red[t] = fmaxf(red[t], red[t+s]); __syncthreads(); }
    mx = red[0]; __syncthreads();
    float e[2]; float se = 0.f;
    #pragma unroll
    for (int j = 0; j < 2; j++) { e[j] = f0[j] ? __expf(a0[j]-mx) : 0.f; se += e[j]; }
    red[t] = se; __syncthreads();
    for (int s = 128; s; s >>= 1) { if (t < s) red[t] += red[t+s]; __syncthreads(); }
    se = red[0];
    float inv = 1.f / fmaxf(se, 1e-8f);
    #pragma unroll
    for (int j = 0; j < 2; j++) { int l = t + j*256; gate[b*L_+l] = e[j]*inv; }
}

// ---- G_h[b] = xb[b] @ A_h  (row tiles < sep only) — R10 structure (proven) ----
__global__ __launch_bounds__(256) void k_gmat(const bf16* __restrict__ xb,
                                              const bf16* __restrict__ AT,
                                              const int* __restrict__ seg,
                                              bf16* __restrict__ G) {
    int b = blockIdx.x;
    int mt = blockIdx.y / 6, nt = blockIdx.y % 6;
    int h = blockIdx.z;
    int sep = seg[b*2];
    int row0 = mt*128;
    if (row0 >= sep) return;
    const bf16* Asrc = xb + (size_t)b*L_*D_;
    const bf16* Bsrc = AT + (size_t)h*D_*D_;
    bf16* outp = G + (size_t)(h*B_ + b)*L_*D_;
    __shared__ bf16 As[128*32];
    __shared__ bf16 Bs[128*32];
    int t = threadIdx.x;
    int wave = t >> 6, lane = t & 63;
    int quad = lane >> 4, l16 = lane & 15;
    int wm = wave >> 1, wn = wave & 1;
    int col0 = nt * 128;

    v4f acc[4][4];
    #pragma unroll
    for (int i = 0; i < 4; i++)
        #pragma unroll
        for (int j = 0; j < 4; j++) acc[i][j] = (v4f){0.f,0.f,0.f,0.f};

    int srow = lane >> 2;
    int skx  = ((lane & 3) ^ (srow & 3)) * 8;
    const bf16* agp0 = Asrc + (size_t)(row0 + wave*32 + srow)*D_ + skx;
    const bf16* agp1 = agp0 + 16*D_;
    const bf16* bgp0 = Bsrc + (size_t)(col0 + wave*32 + srow)*D_ + skx;
    const bf16* bgp1 = bgp0 + 16*D_;
    bf16* al0 = &As[(wave*2    )*512];
    bf16* al1 = &As[(wave*2 + 1)*512];
    bf16* bl0 = &Bs[(wave*2    )*512];
    bf16* bl1 = &Bs[(wave*2 + 1)*512];
    int aoffA[4], aoffB[4];
    #pragma unroll
    for (int i = 0; i < 4; i++) {
        aoffA[i] = (wm*4 + i)*512 + (l16*4 + (quad ^ (l16 & 3)))*8;
        aoffB[i] = (wn*4 + i)*512 + (l16*4 + (quad ^ (l16 & 3)))*8;
    }

    for (int k0 = 0; k0 < D_; k0 += 32) {
        gl_lds16(agp0 + k0, al0);
        gl_lds16(agp1 + k0, al1);
        gl_lds16(bgp0 + k0, bl0);
        gl_lds16(bgp1 + k0, bl1);
        __syncthreads();
        v8s af[4], bf[4];
        #pragma unroll
        for (int i = 0; i < 4; i++)
            af[i] = *reinterpret_cast<const v8s*>(&As[aoffA[i]]);
        #pragma unroll
        for (int j = 0; j < 4; j++)
            bf[j] = *reinterpret_cast<const v8s*>(&Bs[aoffB[j]]);
        #pragma unroll
        for (int i = 0; i < 4; i++)
            #pragma unroll
            for (int j = 0; j < 4; j++)
                acc[i][j] = __builtin_amdgcn_mfma_f32_16x16x32_bf16(af[i], bf[j], acc[i][j], 0, 0, 0);
        __syncthreads();
    }
    #pragma unroll
    for (int i = 0; i < 4; i++)
        #pragma unroll
        for (int j = 0; j < 4; j++) {
            int n = col0 + wn*64 + j*16 + l16;
            #pragma unroll
            for (int r = 0; r < 4; r++) {
                int m = row0 + wm*64 + i*16 + quad*4 + r;
                outp[(size_t)m*D_ + n] = __float2bfloat16(acc[i][j][r]);
            }
        }
}

// ------ scores via G.x^T: G staged in LDS; no max-subtraction (logits bounded) ----
__global__ __launch_bounds__(256) void k_score(const bf16* __restrict__ G,
                                               const bf16* __restrict__ xb,
                                               const int* __restrict__ ids,
                                               const int* __restrict__ seg,
                                               const float* __restrict__ gate,
                                               const int* pad_p,
                                               const float* __restrict__ csup,
                                               const float* __restrict__ ccon,
                                               const float* __restrict__ crep,
                                               const float* __restrict__ rcon,
                                               const float* __restrict__ vecs,
                                               float* __restrict__ w_sup,
                                               float* __restrict__ w_rep) {
    int b = blockIdx.x, rt = blockIdx.y;          // x=batch for XCD L2 affinity
    int sep = seg[b*2];
    int r0 = rt*16;
    if (r0 >= sep) return;
    int pad = *pad_p;
    int wave = threadIdx.x >> 6, lane = threadIdx.x & 63;
    int quad = lane >> 4, l16 = lane & 15;
    const float inv  = 0.03608439182435161f;      // 1/sqrt(768)
    int ct0 = (sep + 1) >> 4;                     // first tile containing cols > sep

    // --- stage G[h][r0..r0+16][0..768): coalesced read, write to identity slot ---
    __shared__ bf16 Gs[3*12288];                  // 73,728 B
    {
        int srow = lane >> 2;                     // 4 lanes per row (coalesced 64B)
        int sk8  = lane & 3;
        int slot = (sk8 << 4) | srow;
        for (int c = wave; c < 72; c += 4) {
            int h = c / 24, kb = c % 24;
            const bf16* gsrc = G + (size_t)(h*B_ + b)*L_*D_ + (size_t)(r0 + srow)*D_ + kb*32 + sk8*8;
            v8s v = *reinterpret_cast<const v8s*>(gsrc);
            *reinterpret_cast<v8s*>(&Gs[h*12288 + kb*512 + slot*8]) = v;
        }
    }

    int tile[6]; bool act[6];
    #pragma unroll
    for (int i = 0; i < 6; i++) {
        int ctv = ct0 + wave + 4*i;
        act[i] = ctv < 32;
        tile[i] = act[i] ? ctv : 31;
    }
    int koff[6];
    #pragma unroll
    for (int i = 0; i < 6; i++) koff[i] = (tile[i]*16 + l16)*D_ + quad*8;

    v4f S[6], C[6], R[6];
    #pragma unroll
    for (int i = 0; i < 6; i++) { S[i] = (v4f){0,0,0,0}; C[i] = (v4f){0,0,0,0}; R[i] = (v4f){0,0,0,0}; }

    const bf16* xrow = xb + (size_t)b*L_*D_;

    __syncthreads();                              // staging complete
    for (int k0 = 0, kb = 0; k0 < D_; k0 += 32, kb++) {
        v8s as = *reinterpret_cast<const v8s*>(&Gs[          kb*512 + lane*8]);
        v8s ac = *reinterpret_cast<const v8s*>(&Gs[12288 + kb*512 + lane*8]);
        v8s ar = *reinterpret_cast<const v8s*>(&Gs[24576 + kb*512 + lane*8]);
        #pragma unroll
        for (int i = 0; i < 6; i++) {
            v8s kf = *reinterpret_cast<const v8s*>(xrow + koff[i] + k0);
            S[i] = __builtin_amdgcn_mfma_f32_16x16x32_bf16(as, kf, S[i], 0, 0, 0);
            C[i] = __builtin_amdgcn_mfma_f32_16x16x32_bf16(ac, kf, C[i], 0, 0, 0);
            R[i] = __builtin_amdgcn_mfma_f32_16x16x32_bf16(ar, kf, R[i], 0, 0, 0);
        }
    }

    bool opt[6];
    float cs_v[6], cc_v[6], cr_v[6];
    #pragma unroll
    for (int i = 0; i < 6; i++) {
        int c = tile[i]*16 + l16;
        opt[i] = act[i] && (c > sep) && (ids[b*L_ + c] != pad);
        cs_v[i] = csup[b*L_ + c];
        cc_v[i] = ccon[b*L_ + c];
        cr_v[i] = crep[b*L_ + c];
    }
    float rc_r[4];
    #pragma unroll
    for (int r = 0; r < 4; r++) rc_r[r] = rcon[b*L_ + r0 + quad*4 + r];
    float dcon = vecs[3072];

    // exp of logits directly (|logit| <= ~5: fp32-exact without max subtraction)
    float ssum[4] = {0,0,0,0}, rsum[4] = {0,0,0,0};
    #pragma unroll
    for (int i = 0; i < 6; i++)
        #pragma unroll
        for (int r = 0; r < 4; r++) {
            float sl = (S[i][r] + cs_v[i]) * inv;
            float cl = fast_tanh((C[i][r] + cc_v[i] + rc_r[r] + dcon) * inv);
            float rl = (R[i][r] + cr_v[i]) * inv + cl;
            float es = opt[i] ? __expf(sl) : 0.f;
            float er = opt[i] ? __expf(rl) : 0.f;
            S[i][r] = es; R[i][r] = er;
            ssum[r] += es; rsum[r] += er;
        }
    #pragma unroll
    for (int d = 1; d < 16; d <<= 1)
        #pragma unroll
        for (int r = 0; r < 4; r++) {
            ssum[r] += __shfl_xor(ssum[r], d);
            rsum[r] += __shfl_xor(rsum[r], d);
        }
    __shared__ float reds[2][16][4];
    if (l16 == 0)
        #pragma unroll
        for (int r = 0; r < 4; r++) {
            reds[0][quad*4+r][wave] = ssum[r];
            reds[1][quad*4+r][wave] = rsum[r];
        }
    __syncthreads();
    float gs_[4], gr_[4];
    #pragma unroll
    for (int r = 0; r < 4; r++) {
        int row = quad*4 + r;
        float st = reds[0][row][0] + reds[0][row][1] + reds[0][row][2] + reds[0][row][3];
        float rtot = reds[1][row][0] + reds[1][row][1] + reds[1][row][2] + reds[1][row][3];
        float g = gate[b*L_ + r0 + row];
        gs_[r] = g / st;
        gr_[r] = g / rtot;
    }

    #pragma unroll
    for (int i = 0; i < 6; i++) {
        float cs = 0.f, cr = 0.f;
        #pragma unroll
        for (int r = 0; r < 4; r++) { cs += S[i][r]*gs_[r]; cr += R[i][r]*gr_[r]; }
        cs += __shfl_xor(cs, 16); cs += __shfl_xor(cs, 32);
        cr += __shfl_xor(cr, 16); cr += __shfl_xor(cr, 32);
        if (act[i] && quad == 0) {
            int c = tile[i]*16 + l16;
            atomicAdd(&w_sup[b*L_ + c], cs);
            atomicAdd(&w_rep[b*L_ + c], cr);
        }
    }
}

// ---- 3 gemvs over L (bf16 x): partials into fused[32][2304] via atomics --
__global__ __launch_bounds__(256) void k_fused(const bf16* __restrict__ xb,
                                               const float* __restrict__ gate,
                                               const float* __restrict__ wrep,
                                               const float* __restrict__ wsup,
                                               float* __restrict__ fused) {
    int b = blockIdx.x, ch = blockIdx.y, t = threadIdx.x;
    int l0 = ch*64;
    const bf16* xb_ = xb + (size_t)b*L_*D_;
    float a0=0,a1=0,a2=0, r0=0,r1=0,r2=0, s0=0,s1=0,s2=0;
    for (int l = l0; l < l0+64; l++) {
        float g = gate[b*L_+l], wr = wrep[b*L_+l], wv = wsup[b*L_+l];
        if (g == 0.f && wr == 0.f && wv == 0.f) continue;
        float x0 = __bfloat162float(xb_[l*D_ + t]);
        float x1 = __bfloat162float(xb_[l*D_ + t + 256]);
        float x2 = __bfloat162float(xb_[l*D_ + t + 512]);
        a0 += g*x0;  a1 += g*x1;  a2 += g*x2;
        r0 += wr*x0; r1 += wr*x1; r2 += wr*x2;
        s0 += wv*x0; s1 += wv*x1; s2 += wv*x2;
    }
    float* f = fused + (size_t)b*2304;
    atomicAdd(&f[t],        a0); atomicAdd(&f[t+256],      a1); atomicAdd(&f[t+512],      a2);
    atomicAdd(&f[768+t],    r0); atomicAdd(&f[768+t+256],  r1); atomicAdd(&f[768+t+512],  r2);
    atomicAdd(&f[1536+t],   s0); atomicAdd(&f[1536+t+256], s1); atomicAdd(&f[1536+t+512], s2);
}

// ---- MLP layer 1, split-K: partial sums into h1pre via atomics ----
__global__ __launch_bounds__(256) void k_mlp1(const float* __restrict__ fused,
                                              const float* __restrict__ W1,
                                              float* __restrict__ h1pre) {
    int c0 = blockIdx.x*64, k0 = blockIdx.y*128;
    int t = threadIdx.x;
    __shared__ float fsl[32][132];
    for (int i = t*4; i < 32*128; i += 1024) {
        int b = i >> 7, k = i & 127;
        const float4 v = *reinterpret_cast<const float4*>(&fused[(size_t)b*2304 + k0 + k]);
        fsl[b][k] = v.x; fsl[b][k+1] = v.y; fsl[b][k+2] = v.z; fsl[b][k+3] = v.w;
    }
    __syncthreads();
    int c = c0 + (t & 63), bg = (t >> 6) * 8;
    float acc[8] = {0,0,0,0,0,0,0,0};
    for (int k = 0; k < 128; k++) {
        float w = W1[(size_t)(k0+k)*D_ + c];
        #pragma unroll
        for (int b = 0; b < 8; b++) acc[b] += fsl[bg+b][k] * w;
    }
    #pragma unroll
    for (int b = 0; b < 8; b++) atomicAdd(&h1pre[(size_t)(bg+b)*D_ + c], acc[b]);
}

// ---- MLP layer 2, split-K: relu(h1pre+b1) on load; partials into opre ----
__global__ __launch_bounds__(256) void k_mlp2(const float* __restrict__ h1pre,
                                              const float* __restrict__ b1,
                                              const float* __restrict__ W2,
                                              float* __restrict__ opre) {
    int c0 = blockIdx.x*64, k0 = blockIdx.y*128;
    int t = threadIdx.x;
    __shared__ float fsl[32][132];
    for (int i = t*4; i < 32*128; i += 1024) {
        int b = i >> 7, k = i & 127;
        const float4 v = *reinterpret_cast<const float4*>(&h1pre[(size_t)b*D_ + k0 + k]);
        const float4 bb = *reinterpret_cast<const float4*>(&b1[k0 + k]);
        fsl[b][k]   = fmaxf(v.x + bb.x, 0.f);
        fsl[b][k+1] = fmaxf(v.y + bb.y, 0.f);
        fsl[b][k+2] = fmaxf(v.z + bb.z, 0.f);
        fsl[b][k+3] = fmaxf(v.w + bb.w, 0.f);
    }
    __syncthreads();
    int c = c0 + (t & 63), bg = (t >> 6) * 8;
    float acc[8] = {0,0,0,0,0,0,0,0};
    for (int k = 0; k < 128; k++) {
        float w = W2[(size_t)(k0+k)*D_ + c];
        #pragma unroll
        for (int b = 0; b < 8; b++) acc[b] += fsl[bg+b][k] * w;
    }
    #pragma unroll
    for (int b = 0; b < 8; b++) atomicAdd(&opre[(size_t)(bg+b)*D_ + c], acc[b]);
}

// ---- bias2 + LayerNorm: one block per batch ----
__global__ __launch_bounds__(256) void k_ln(const float* __restrict__ opre,
                                            const float* __restrict__ b2,
                                            const float* __restrict__ lng,
                                            const float* __restrict__ lnb,
                                            float* __restrict__ out) {
    int b = blockIdx.x, t = threadIdx.x;
    __shared__ float red[256];
    float v0 = opre[(size_t)b*D_ + t]       + b2[t];
    float v1 = opre[(size_t)b*D_ + t + 256] + b2[t+256];
    float v2 = opre[(size_t)b*D_ + t + 512] + b2[t+512];
    float sum = v0+v1+v2, sq = v0*v0+v1*v1+v2*v2;
    red[t] = sum; __syncthreads();
    for (int s = 128; s; s >>= 1) { if (t < s) red[t] += red[t+s]; __syncthreads(); }
    sum = red[0]; __syncthreads();
    red[t] = sq; __syncthreads();
    for (int s = 128; s; s >>= 1) { if (t < s) red[t] += red[t+s]; __syncthreads(); }
    sq = red[0];
    float mu = sum / 768.f;
    float var = sq / 768.f - mu*mu;
    float rstd = rsqrtf(var + 1e-5f);
    out[(size_t)b*D_ + t]       = (v0-mu)*rstd*lng[t]     + lnb[t];
    out[(size_t)b*D_ + t + 256] = (v1-mu)*rstd*lng[t+256] + lnb[t+256];
    out[(size_t)b*D_ + t + 512] = (v2-mu)*rstd*lng[t+512] + lnb[t+512];
}

extern "C" void kernel_launch(void* const* d_in, const int* in_sizes, int n_in,
                              void* d_out, int out_size, void* d_ws, size_t ws_size,
                              hipStream_t stream) {
    const float* x      = (const float*)d_in[0];
    const int*   ids    = (const int*)d_in[1];
    const int*   pad_p  = (const int*)d_in[2];
    const int*   sep_p  = (const int*)d_in[3];
    const float* W_anom = (const float*)d_in[4];
    const float* b_anom = (const float*)d_in[5];
    const float* Wq_sup = (const float*)d_in[6];  const float* bq_sup = (const float*)d_in[7];
    const float* Wk_sup = (const float*)d_in[8];  const float* bk_sup = (const float*)d_in[9];
    const float* Wq_con = (const float*)d_in[10]; const float* bq_con = (const float*)d_in[11];
    const float* Wk_con = (const float*)d_in[12]; const float* bk_con = (const float*)d_in[13];
    const float* Wq_rep = (const float*)d_in[14]; const float* bq_rep = (const float*)d_in[15];
    const float* Wk_rep = (const float*)d_in[16]; const float* bk_rep = (const float*)d_in[17];
    const float* W1     = (const float*)d_in[18]; const float* b1     = (const float*)d_in[19];
    const float* W2     = (const float*)d_in[20]; const float* b2     = (const float*)d_in[21];
    const float* lng    = (const float*)d_in[22]; const float* lnb    = (const float*)d_in[23];
    float* out = (float*)d_out;

    char* w = (char*)d_ws;
    bf16*  xb    = (bf16*)(w);                      // 25,165,824
    bf16*  AT    = (bf16*)(w + 25165824);           //  3,538,944
    bf16*  G     = (bf16*)(w + 28704768);           // 75,497,472
    float* vecs  = (float*)(w + 104202240);         //     16,384
    float* anom  = (float*)(w + 104218624);         //     65,536
    float* gate  = (float*)(w + 104284160);         //     65,536
    float* csup  = (float*)(w + 104349696);         //     65,536
    float* ccon  = (float*)(w + 104415232);         //     65,536
    float* crep  = (float*)(w + 104480768);         //     65,536
    float* rcon  = (float*)(w + 104546304);         //     65,536
    float* wsup  = (float*)(w + 104611840);         //     65,536
    float* wrep  = (float*)(w + 104677376);         //     65,536
    float* fused = (float*)(w + 104742912);         //    294,912
    float* h1pre = (float*)(w + 105037824);         //     98,304
    float* opre  = (float*)(w + 105136128);         //     98,304
    int*   seg   = (int*)  (w + 105234432);         //        256

    k_setup<<<801, 256, 0, stream>>>(ids, pad_p, sep_p, seg,
                                     Wk_sup, bq_sup, Wk_con, bq_con, Wk_rep, bq_rep, Wq_con, bk_con, vecs);
    k_prepw<<<4528, 256, 0, stream>>>(x, W_anom, b_anom, vecs, xb, anom, csup, ccon, crep, rcon,
                                      Wq_sup, Wk_sup, Wq_con, Wk_con, Wq_rep, Wk_rep, AT);
    // k_gate also zero-inits wsup..opre (contiguous 622,592 B = 38,912 float4)
    k_gate<<<B_, 256, 0, stream>>>(anom, ids, seg, pad_p, gate, (float4*)wsup, 38912);
    k_gmat<<<dim3(B_, 12, 3), 256, 0, stream>>>(xb, AT, seg, G);
    k_score<<<dim3(B_, 16), 256, 0, stream>>>(G, xb, ids, seg, gate, pad_p,
                                              csup, ccon, crep, rcon, vecs, wsup, wrep);
    k_fused<<<dim3(B_, 8), 256, 0, stream>>>(xb, gate, wrep, wsup, fused);
    k_mlp1<<<dim3(12, 18), 256, 0, stream>>>(fused, W1, h1pre);
    k_mlp2<<<dim3(12, 6), 256, 0, stream>>>(h1pre, b1, W2, opre);
    k_ln<<<B_, 256, 0, stream>>>(opre, b2, lng, lnb, out);
}